// Round 10
// baseline (228.751 us; speedup 1.0000x reference)
//
#include <hip/hip_runtime.h>

typedef unsigned short u16;
using short8 = __attribute__((ext_vector_type(8))) short;
using f32x4  = __attribute__((ext_vector_type(4))) float;

#define SCALE 0.15811388300841897f  // 40^-0.5

__device__ __forceinline__ u16 f2bf(float f) {
  unsigned int u = __float_as_uint(f);
  u += 0x7fffu + ((u >> 16) & 1u);   // RNE
  return (u16)(u >> 16);
}

// ---------------- ws layout (u16 units) ----------------
// wqt [320][320]        @ 0        (102400)  Wq^T * SCALE, bf16
// wot [320][320]        @ 102400   (102400)  Wo^T, bf16
// wkt [320][768]        @ 204800   (245760)  Wk^T, bf16
// wvt [320][768]        @ 450560   (245760)  Wv^T, bf16
// kbf [16][8][80][64]   @ 696320   (655360)  K  (m pad->80, d pad->64 zeroed)
// vt  [16][8][48][96]   @ 1351680  (589824)  V^T (d pad->48 zeroed, m pad->96 zeroed)
// qg  [65536][320]      @ 1941504  (20971520) x bf16 -> Q bf16 -> O bf16, all in place
// slack 64 u16          @ 22913024 (zeroed by xconv; absorbs benign A-frag overrun)

// ============ kernel 0: LDS-tiled weight transpose + bf16 ============
__global__ void prep_transpose(const float* __restrict__ Wq, const float* __restrict__ Wo,
                               const float* __restrict__ Wk, const float* __restrict__ Wv,
                               u16* __restrict__ wqt, u16* __restrict__ wot,
                               u16* __restrict__ wkt, u16* __restrict__ wvt) {
  __shared__ float ld[64][65];
  const int bid = blockIdx.x;
  const float* src; u16* dst; int K; float scale; int tk, tn;
  if (bid < 25)       { src = Wq; dst = wqt; K = 320; scale = SCALE; tk = bid / 5;         tn = bid % 5; }
  else if (bid < 50)  { src = Wo; dst = wot; K = 320; scale = 1.f;   tk = (bid - 25) / 5;  tn = (bid - 25) % 5; }
  else if (bid < 110) { src = Wk; dst = wkt; K = 768; scale = 1.f;   tk = (bid - 50) / 5;  tn = (bid - 50) % 5; }
  else                { src = Wv; dst = wvt; K = 768; scale = 1.f;   tk = (bid - 110) / 5; tn = (bid - 110) % 5; }
  const int c = threadIdx.x & 63, r0 = threadIdx.x >> 6;
  for (int rr = r0; rr < 64; rr += 4)
    ld[rr][c] = src[(size_t)(tk * 64 + rr) * 320 + tn * 64 + c];
  __syncthreads();
  for (int rr = r0; rr < 64; rr += 4)
    dst[(size_t)(tn * 64 + rr) * K + tk * 64 + c] = f2bf(ld[c][rr] * scale);
}

// ============ kernel 1: x f32 -> bf16 streaming conversion (into qg) ============
__global__ __launch_bounds__(256)
void xconv(const float* __restrict__ x, u16* __restrict__ xbf) {
  const size_t idx = (size_t)blockIdx.x * 256 + threadIdx.x;
  const size_t stride = (size_t)gridDim.x * 256;
  const size_t total = (size_t)65536 * 320 / 8;   // 8 elems per iter
  for (size_t g = idx; g < total; g += stride) {
    const float4* src = reinterpret_cast<const float4*>(x + g * 8);
    float4 a = src[0], b = src[1];
    uint4 o;
    o.x = (unsigned)f2bf(a.x) | ((unsigned)f2bf(a.y) << 16);
    o.y = (unsigned)f2bf(a.z) | ((unsigned)f2bf(a.w) << 16);
    o.z = (unsigned)f2bf(b.x) | ((unsigned)f2bf(b.y) << 16);
    o.w = (unsigned)f2bf(b.z) | ((unsigned)f2bf(b.w) << 16);
    *reinterpret_cast<uint4*>(xbf + g * 8) = o;
  }
  if (blockIdx.x == 0 && threadIdx.x < 64) xbf[(size_t)65536 * 320 + threadIdx.x] = 0;  // slack
}

// ============ kernel 2: K,V projection via MFMA (split K/V) ============
__global__ __launch_bounds__(256, 1)
void kv_mfma(const float* __restrict__ ctx,
             const u16* __restrict__ wkt, const u16* __restrict__ wvt,
             u16* __restrict__ kbf, u16* __restrict__ vt) {
  const int b = blockIdx.x, z = blockIdx.y;
  const int tid = threadIdx.x;
  const int w = tid >> 6, l = tid & 63, l16 = l & 15, lhi = l >> 4;
  __shared__ __align__(16) u16 sctx[80][776];

  for (int i = tid; i < 80 * 192; i += 256) {
    int row = i / 192, c4 = (i - row * 192) * 4;
    ushort4 u;
    if (row < 77) {
      float4 v = *reinterpret_cast<const float4*>(&ctx[(size_t)(b * 77 + row) * 768 + c4]);
      u.x = f2bf(v.x); u.y = f2bf(v.y); u.z = f2bf(v.z); u.w = f2bf(v.w);
    } else u = (ushort4){0, 0, 0, 0};
    *reinterpret_cast<ushort4*>(&sctx[row][c4]) = u;
  }
  if (z == 0) {
    for (int i = tid; i < 8 * 80 * 3; i += 256) {
      int hm = i / 3, q = i - hm * 3;
      int h = hm / 80, m = hm - h * 80;
      *reinterpret_cast<uint4*>(&kbf[(((size_t)b * 8 + h) * 80 + m) * 64 + 40 + q * 8]) = (uint4){0, 0, 0, 0};
    }
  } else {
    for (int i = tid; i < 8 * 48 * 2; i += 256) {
      int hd = i / 2, q = i - hd * 2;
      int h = hd / 48, d = hd - h * 48;
      *reinterpret_cast<uint4*>(&vt[(((size_t)b * 8 + h) * 48 + d) * 96 + 80 + q * 8]) = (uint4){0, 0, 0, 0};
    }
    for (int i = tid; i < 8 * 8 * 10; i += 256) {
      int h = i / 80, rem = i - h * 80;
      int d = 40 + rem / 10, q = rem - (rem / 10) * 10;
      *reinterpret_cast<uint4*>(&vt[(((size_t)b * 8 + h) * 48 + d) * 96 + q * 8]) = (uint4){0, 0, 0, 0};
    }
  }
  __syncthreads();

  f32x4 acc[5][5];
  #pragma unroll
  for (int rt = 0; rt < 5; ++rt)
    #pragma unroll
    for (int nt = 0; nt < 5; ++nt) acc[rt][nt] = (f32x4){0.f, 0.f, 0.f, 0.f};

  const u16* wbase = (z == 0 ? wkt : wvt) + (size_t)(w * 80) * 768;
  #pragma unroll 2
  for (int ks = 0; ks < 24; ++ks) {
    short8 af[5];
    #pragma unroll
    for (int rt = 0; rt < 5; ++rt)
      af[rt] = *reinterpret_cast<const short8*>(&sctx[rt * 16 + l16][ks * 32 + lhi * 8]);
    short8 bf[5];
    #pragma unroll
    for (int nt = 0; nt < 5; ++nt)
      bf[nt] = *reinterpret_cast<const short8*>(&wbase[(size_t)(nt * 16 + l16) * 768 + ks * 32 + lhi * 8]);
    #pragma unroll
    for (int rt = 0; rt < 5; ++rt)
      #pragma unroll
      for (int nt = 0; nt < 5; ++nt)
        acc[rt][nt] = __builtin_amdgcn_mfma_f32_16x16x32_bf16(af[rt], bf[nt], acc[rt][nt], 0, 0, 0);
  }

  if (z == 0) {
    #pragma unroll
    for (int rt = 0; rt < 5; ++rt)
      #pragma unroll
      for (int nt = 0; nt < 5; ++nt) {
        int c = w * 80 + nt * 16 + l16, h = c / 40, d = c - h * 40;
        #pragma unroll
        for (int r = 0; r < 4; ++r) {
          int m = rt * 16 + lhi * 4 + r;
          kbf[(((size_t)b * 8 + h) * 80 + m) * 64 + d] = f2bf(m < 77 ? acc[rt][nt][r] : 0.f);
        }
      }
  } else {
    #pragma unroll
    for (int rt = 0; rt < 5; ++rt)
      #pragma unroll
      for (int nt = 0; nt < 5; ++nt) {
        int c = w * 80 + nt * 16 + l16, h = c / 40, d = c - h * 40;
        #pragma unroll
        for (int r = 0; r < 4; ++r) {
          int m = rt * 16 + lhi * 4 + r;
          vt[(((size_t)b * 8 + h) * 48 + d) * 96 + m] = f2bf(m < 77 ? acc[rt][nt][r] : 0.f);
        }
      }
  }
}

// ============ kernel 3: Q projection GEMM (bf16 in, in-place, full unroll) ============
__global__ __launch_bounds__(256, 3)
void qproj(u16* __restrict__ qg, const u16* __restrict__ wqt) {
  const int tid = threadIdx.x;
  const int w = tid >> 6, l = tid & 63, l16 = l & 15, lhi = l >> 4;
  const int r0 = blockIdx.x * 64;
  __shared__ __align__(16) u16 xs[64][328];   // 41,984 B -> 3 blocks/CU

  for (int i = tid; i < 64 * 40; i += 256) {
    int row = i / 40, c8 = (i - row * 40) * 8;
    *reinterpret_cast<uint4*>(&xs[row][c8]) =
        *reinterpret_cast<const uint4*>(&qg[(size_t)(r0 + row) * 320 + c8]);
  }
  __syncthreads();

  f32x4 acc[4][5];
  #pragma unroll
  for (int rt = 0; rt < 4; ++rt)
    #pragma unroll
    for (int nt = 0; nt < 5; ++nt) acc[rt][nt] = (f32x4){0.f, 0.f, 0.f, 0.f};
  #pragma unroll
  for (int ks = 0; ks < 10; ++ks) {
    short8 af[4];
    #pragma unroll
    for (int rt = 0; rt < 4; ++rt)
      af[rt] = *reinterpret_cast<const short8*>(&xs[rt * 16 + l16][ks * 32 + lhi * 8]);
    #pragma unroll
    for (int nt = 0; nt < 5; ++nt) {
      short8 bf = *reinterpret_cast<const short8*>(&wqt[(size_t)(w * 80 + nt * 16 + l16) * 320 + ks * 32 + lhi * 8]);
      #pragma unroll
      for (int rt = 0; rt < 4; ++rt)
        acc[rt][nt] = __builtin_amdgcn_mfma_f32_16x16x32_bf16(af[rt], bf, acc[rt][nt], 0, 0, 0);
    }
  }
  __syncthreads();   // all xs reads done before overwrite
  #pragma unroll
  for (int rt = 0; rt < 4; ++rt)
    #pragma unroll
    for (int nt = 0; nt < 5; ++nt) {
      int col = w * 80 + nt * 16 + l16;
      #pragma unroll
      for (int r = 0; r < 4; ++r)
        xs[rt * 16 + lhi * 4 + r][col] = f2bf(acc[rt][nt][r]);
    }
  __syncthreads();
  for (int i = tid; i < 64 * 40; i += 256) {
    int row = i / 40, c8 = (i - row * 40) * 8;
    *reinterpret_cast<uint4*>(&qg[(size_t)(r0 + row) * 320 + c8]) =
        *reinterpret_cast<const uint4*>(&xs[row][c8]);
  }
}

// ============ kernel 4: attention (no-max softmax, dbuf P, one fence/head) ============
// grid (64 qtiles, 16 b), 512 thr (8 waves), LDS 53 KB -> 3 blocks/CU.
__global__ __launch_bounds__(512, 6)
void attn_sm(u16* __restrict__ qg, const u16* __restrict__ kbf,
             const u16* __restrict__ vtp) {
  const int b  = blockIdx.y;
  const int q0 = blockIdx.x * 64;
  const int tid = threadIdx.x;
  const int w   = tid >> 6;
  const int l   = tid & 63;
  const int l16 = l & 15;
  const int lhi = l >> 4;
  const int wq  = w & 3;
  const int hg  = w >> 2;

  __shared__ __align__(16) u16 Pt[8][2][16][104];   // 53,248 B, per-wave double-buffered

  if (l < 64) {
    int s = l >> 5, r = (l >> 1) & 15, q = l & 1;
    *reinterpret_cast<uint4*>(&Pt[w][s][r][80 + 8 * q]) = (uint4){0u, 0u, 0u, 0u};
  }

  const size_t rowbase = (size_t)(b * 4096 + q0 + wq * 16);

  for (int hi = 0; hi < 4; ++hi) {
    const int h = hg * 4 + hi;
    const int slot = hi & 1;
    const u16* kh = kbf + ((size_t)(b * 8 + h)) * 80 * 64;
    const u16* vh = vtp + ((size_t)(b * 8 + h)) * 48 * 96;
    // S = Q K^T (scores ~N(0,1): SCALE folded into Wq)
    f32x4 sacc[5];
    #pragma unroll
    for (int mt = 0; mt < 5; ++mt) sacc[mt] = (f32x4){0.f, 0.f, 0.f, 0.f};
    #pragma unroll
    for (int ks = 0; ks < 2; ++ks) {
      short8 a = *reinterpret_cast<const short8*>(
          &qg[(rowbase + l16) * 320 + h * 40 + ks * 32 + lhi * 8]);
      #pragma unroll
      for (int mt = 0; mt < 5; ++mt) {
        short8 bb = *reinterpret_cast<const short8*>(&kh[(mt * 16 + l16) * 64 + ks * 32 + lhi * 8]);
        sacc[mt] = __builtin_amdgcn_mfma_f32_16x16x32_bf16(a, bb, sacc[mt], 0, 0, 0);
      }
    }
    // softmax without max-shift (|s| <= ~7 by construction; exp(s) <= ~1100, f32-safe)
    #pragma unroll
    for (int r = 0; r < 4; ++r) {
      float ev[5];
      float sum = 0.f;
      #pragma unroll
      for (int mt = 0; mt < 5; ++mt) {
        float s = (mt * 16 + l16 >= 77) ? -1e30f : sacc[mt][r];
        ev[mt] = __expf(s);
        sum += ev[mt];
      }
      sum += __shfl_xor(sum, 1);
      sum += __shfl_xor(sum, 2);
      sum += __shfl_xor(sum, 4);
      sum += __shfl_xor(sum, 8);
      float rs = 1.f / sum;
      int row = lhi * 4 + r;
      #pragma unroll
      for (int mt = 0; mt < 5; ++mt)
        Pt[w][slot][row][mt * 16 + l16] = f2bf(ev[mt] * rs);
    }
    // fence: P writes complete before PV reads (same wave)
    asm volatile("s_waitcnt lgkmcnt(0)" ::: "memory");
    __builtin_amdgcn_sched_barrier(0);
    f32x4 oacc[3];
    #pragma unroll
    for (int nt = 0; nt < 3; ++nt) oacc[nt] = (f32x4){0.f, 0.f, 0.f, 0.f};
    #pragma unroll
    for (int ks = 0; ks < 3; ++ks) {
      short8 a = *reinterpret_cast<const short8*>(&Pt[w][slot][l16][ks * 32 + lhi * 8]);
      #pragma unroll
      for (int nt = 0; nt < 3; ++nt) {
        short8 bb = *reinterpret_cast<const short8*>(&vh[(nt * 16 + l16) * 96 + ks * 32 + lhi * 8]);
        oacc[nt] = __builtin_amdgcn_mfma_f32_16x16x32_bf16(a, bb, oacc[nt], 0, 0, 0);
      }
    }
    // no WAR fence needed: next head writes the other P slot
    #pragma unroll
    for (int nt = 0; nt < 3; ++nt) {
      int d = nt * 16 + l16;
      if (d < 40) {
        #pragma unroll
        for (int r = 0; r < 4; ++r)
          qg[(rowbase + lhi * 4 + r) * 320 + h * 40 + d] = f2bf(oacc[nt][r]);
      }
    }
  }
}

// ============ kernel 5: out-projection GEMM (full unroll) ============
__global__ __launch_bounds__(256, 4)
void outproj(const u16* __restrict__ og, const u16* __restrict__ wot,
             const float* __restrict__ bo, float* __restrict__ out) {
  const int tid = threadIdx.x;
  const int w = tid >> 6, l = tid & 63, l16 = l & 15, lhi = l >> 4;
  const int r0 = blockIdx.x * 64;
  __shared__ __align__(16) u16 os[64][328];

  for (int i = tid; i < 64 * 40; i += 256) {
    int row = i / 40, c8 = (i - row * 40) * 8;
    *reinterpret_cast<uint4*>(&os[row][c8]) =
        *reinterpret_cast<const uint4*>(&og[(size_t)(r0 + row) * 320 + c8]);
  }
  __syncthreads();

  f32x4 acc[4][5];
  #pragma unroll
  for (int rt = 0; rt < 4; ++rt)
    #pragma unroll
    for (int nt = 0; nt < 5; ++nt) acc[rt][nt] = (f32x4){0.f, 0.f, 0.f, 0.f};
  #pragma unroll
  for (int ks = 0; ks < 10; ++ks) {
    short8 af[4];
    #pragma unroll
    for (int rt = 0; rt < 4; ++rt)
      af[rt] = *reinterpret_cast<const short8*>(&os[rt * 16 + l16][ks * 32 + lhi * 8]);
    #pragma unroll
    for (int nt = 0; nt < 5; ++nt) {
      short8 bf = *reinterpret_cast<const short8*>(&wot[(size_t)(w * 80 + nt * 16 + l16) * 320 + ks * 32 + lhi * 8]);
      #pragma unroll
      for (int rt = 0; rt < 4; ++rt)
        acc[rt][nt] = __builtin_amdgcn_mfma_f32_16x16x32_bf16(af[rt], bf, acc[rt][nt], 0, 0, 0);
    }
  }
  #pragma unroll
  for (int nt = 0; nt < 5; ++nt) {
    int col = w * 80 + nt * 16 + l16;
    float bias = bo[col];
    #pragma unroll
    for (int rt = 0; rt < 4; ++rt) {
      #pragma unroll
      for (int r = 0; r < 4; ++r) {
        int row = rt * 16 + lhi * 4 + r;
        out[(size_t)(r0 + row) * 320 + col] = acc[rt][nt][r] + bias;
      }
    }
  }
}

extern "C" void kernel_launch(void* const* d_in, const int* in_sizes, int n_in,
                              void* d_out, int out_size, void* d_ws, size_t ws_size,
                              hipStream_t stream) {
  (void)in_sizes; (void)n_in; (void)out_size; (void)ws_size;
  const float* x       = (const float*)d_in[0];
  const float* context = (const float*)d_in[1];
  const float* Wq      = (const float*)d_in[2];
  const float* Wk      = (const float*)d_in[3];
  const float* Wv      = (const float*)d_in[4];
  const float* Wo      = (const float*)d_in[5];
  const float* bo      = (const float*)d_in[6];
  float* out = (float*)d_out;
  u16* ws = (u16*)d_ws;
  u16* wqt = ws;                 // 102400
  u16* wot = ws + 102400;        // 102400
  u16* wkt = ws + 204800;        // 245760
  u16* wvt = ws + 450560;        // 245760
  u16* kbf = ws + 696320;        // 655360
  u16* vtp = ws + 1351680;       // 589824
  u16* qg  = ws + 1941504;       // 20971520 + 64 slack

  prep_transpose<<<170, 256, 0, stream>>>(Wq, Wo, Wk, Wv, wqt, wot, wkt, wvt);
  xconv<<<2048, 256, 0, stream>>>(x, qg);
  kv_mfma<<<dim3(16, 2), 256, 0, stream>>>(context, wkt, wvt, kbf, vtp);
  qproj<<<1024, 256, 0, stream>>>(qg, wqt);
  attn_sm<<<dim3(64, 16), 512, 0, stream>>>(qg, kbf, vtp);
  outproj<<<1024, 256, 0, stream>>>(qg, wot, bo, out);
}

// Round 11
// 190.323 us; speedup vs baseline: 1.2019x; 1.2019x over previous
//
#include <hip/hip_runtime.h>

typedef unsigned short u16;
using short8 = __attribute__((ext_vector_type(8))) short;
using f32x4  = __attribute__((ext_vector_type(4))) float;

#define SCALE 0.15811388300841897f  // 40^-0.5

__device__ __forceinline__ u16 f2bf(float f) {
  unsigned int u = __float_as_uint(f);
  u += 0x7fffu + ((u >> 16) & 1u);   // RNE
  return (u16)(u >> 16);
}

// ---------------- ws layout (u16 units) ----------------
// wqt [320][320]        @ 0        (102400)  Wq^T * SCALE, bf16
// wot [320][320]        @ 102400   (102400)  Wo^T, bf16
// wkt [320][768]        @ 204800   (245760)  Wk^T, bf16
// wvt [320][768]        @ 450560   (245760)  Wv^T, bf16
// kbf [16][8][80][64]   @ 696320   (655360)  K  (m pad->80, d pad->64 zeroed)
// vt  [16][8][48][96]   @ 1351680  (589824)  V^T (d pad->48 zeroed, m pad->96 zeroed)

// ============ kernel 0: LDS-tiled weight transpose + bf16 ============
__global__ void prep_transpose(const float* __restrict__ Wq, const float* __restrict__ Wo,
                               const float* __restrict__ Wk, const float* __restrict__ Wv,
                               u16* __restrict__ wqt, u16* __restrict__ wot,
                               u16* __restrict__ wkt, u16* __restrict__ wvt) {
  __shared__ float ld[64][65];
  const int bid = blockIdx.x;
  const float* src; u16* dst; int K; float scale; int tk, tn;
  if (bid < 25)       { src = Wq; dst = wqt; K = 320; scale = SCALE; tk = bid / 5;         tn = bid % 5; }
  else if (bid < 50)  { src = Wo; dst = wot; K = 320; scale = 1.f;   tk = (bid - 25) / 5;  tn = (bid - 25) % 5; }
  else if (bid < 110) { src = Wk; dst = wkt; K = 768; scale = 1.f;   tk = (bid - 50) / 5;  tn = (bid - 50) % 5; }
  else                { src = Wv; dst = wvt; K = 768; scale = 1.f;   tk = (bid - 110) / 5; tn = (bid - 110) % 5; }
  const int c = threadIdx.x & 63, r0 = threadIdx.x >> 6;
  for (int rr = r0; rr < 64; rr += 4)
    ld[rr][c] = src[(size_t)(tk * 64 + rr) * 320 + tn * 64 + c];
  __syncthreads();
  for (int rr = r0; rr < 64; rr += 4)
    dst[(size_t)(tn * 64 + rr) * K + tk * 64 + c] = f2bf(ld[c][rr] * scale);
}

// ============ kernel 1: K,V projection via MFMA (split K/V) ============
__global__ __launch_bounds__(256, 1)
void kv_mfma(const float* __restrict__ ctx,
             const u16* __restrict__ wkt, const u16* __restrict__ wvt,
             u16* __restrict__ kbf, u16* __restrict__ vt) {
  const int b = blockIdx.x, z = blockIdx.y;
  const int tid = threadIdx.x;
  const int w = tid >> 6, l = tid & 63, l16 = l & 15, lhi = l >> 4;
  __shared__ __align__(16) u16 sctx[80][776];

  for (int i = tid; i < 80 * 192; i += 256) {
    int row = i / 192, c4 = (i - row * 192) * 4;
    ushort4 u;
    if (row < 77) {
      float4 v = *reinterpret_cast<const float4*>(&ctx[(size_t)(b * 77 + row) * 768 + c4]);
      u.x = f2bf(v.x); u.y = f2bf(v.y); u.z = f2bf(v.z); u.w = f2bf(v.w);
    } else u = (ushort4){0, 0, 0, 0};
    *reinterpret_cast<ushort4*>(&sctx[row][c4]) = u;
  }
  if (z == 0) {
    for (int i = tid; i < 8 * 80 * 3; i += 256) {
      int hm = i / 3, q = i - hm * 3;
      int h = hm / 80, m = hm - h * 80;
      *reinterpret_cast<uint4*>(&kbf[(((size_t)b * 8 + h) * 80 + m) * 64 + 40 + q * 8]) = (uint4){0, 0, 0, 0};
    }
  } else {
    for (int i = tid; i < 8 * 48 * 2; i += 256) {
      int hd = i / 2, q = i - hd * 2;
      int h = hd / 48, d = hd - h * 48;
      *reinterpret_cast<uint4*>(&vt[(((size_t)b * 8 + h) * 48 + d) * 96 + 80 + q * 8]) = (uint4){0, 0, 0, 0};
    }
    for (int i = tid; i < 8 * 8 * 10; i += 256) {
      int h = i / 80, rem = i - h * 80;
      int d = 40 + rem / 10, q = rem - (rem / 10) * 10;
      *reinterpret_cast<uint4*>(&vt[(((size_t)b * 8 + h) * 48 + d) * 96 + q * 8]) = (uint4){0, 0, 0, 0};
    }
  }
  __syncthreads();

  f32x4 acc[5][5];
  #pragma unroll
  for (int rt = 0; rt < 5; ++rt)
    #pragma unroll
    for (int nt = 0; nt < 5; ++nt) acc[rt][nt] = (f32x4){0.f, 0.f, 0.f, 0.f};

  const u16* wbase = (z == 0 ? wkt : wvt) + (size_t)(w * 80) * 768;
  #pragma unroll 2
  for (int ks = 0; ks < 24; ++ks) {
    short8 af[5];
    #pragma unroll
    for (int rt = 0; rt < 5; ++rt)
      af[rt] = *reinterpret_cast<const short8*>(&sctx[rt * 16 + l16][ks * 32 + lhi * 8]);
    short8 bf[5];
    #pragma unroll
    for (int nt = 0; nt < 5; ++nt)
      bf[nt] = *reinterpret_cast<const short8*>(&wbase[(size_t)(nt * 16 + l16) * 768 + ks * 32 + lhi * 8]);
    #pragma unroll
    for (int rt = 0; rt < 5; ++rt)
      #pragma unroll
      for (int nt = 0; nt < 5; ++nt)
        acc[rt][nt] = __builtin_amdgcn_mfma_f32_16x16x32_bf16(af[rt], bf[nt], acc[rt][nt], 0, 0, 0);
  }

  if (z == 0) {
    #pragma unroll
    for (int rt = 0; rt < 5; ++rt)
      #pragma unroll
      for (int nt = 0; nt < 5; ++nt) {
        int c = w * 80 + nt * 16 + l16, h = c / 40, d = c - h * 40;
        #pragma unroll
        for (int r = 0; r < 4; ++r) {
          int m = rt * 16 + lhi * 4 + r;
          kbf[(((size_t)b * 8 + h) * 80 + m) * 64 + d] = f2bf(m < 77 ? acc[rt][nt][r] : 0.f);
        }
      }
  } else {
    #pragma unroll
    for (int rt = 0; rt < 5; ++rt)
      #pragma unroll
      for (int nt = 0; nt < 5; ++nt) {
        int c = w * 80 + nt * 16 + l16, h = c / 40, d = c - h * 40;
        #pragma unroll
        for (int r = 0; r < 4; ++r) {
          int m = rt * 16 + lhi * 4 + r;
          vt[(((size_t)b * 8 + h) * 48 + d) * 96 + m] = f2bf(m < 77 ? acc[rt][nt][r] : 0.f);
        }
      }
  }
}

// ============ kernel 2: fully fused x->Q->attention->out ============
// grid (64 qtiles, 16 b), 512 thr (8 waves), LDS 70.7 KB -> 2 blocks/CU.
// Phase 1: Q = x @ Wq^T (col-split over waves; Q overwrites x tile in LDS).
// Phase 2: per-wave attention (rows wq*16.., heads hg*4..); O overwrites Q in LDS
//          (same wave, same cols; cross-group col overlap reads x K-pad zeros -> 0).
// Phase 3: out = O @ Wo^T + bo, coalesced f32 stores.
__global__ __launch_bounds__(512, 4)
void fused(const float* __restrict__ x, const u16* __restrict__ wqt,
           const u16* __restrict__ kbf, const u16* __restrict__ vtp,
           const u16* __restrict__ wot, const float* __restrict__ bo,
           float* __restrict__ out) {
  const int b  = blockIdx.y;
  const int q0 = blockIdx.x * 64;
  const int tid = threadIdx.x;
  const int w   = tid >> 6;       // 0..7
  const int l   = tid & 63;
  const int l16 = l & 15;
  const int lhi = l >> 4;

  __shared__ __align__(16) u16 Qx[64][344];      // 44,032 B: x -> Q -> O in place
  __shared__ __align__(16) u16 Pt[8][16][104];   // 26,624 B: per-wave P

  // col-tiles (16 cols each, 20 total): waves 0..3 -> 3 tiles, 4..7 -> 2 (+clamped dup,
  // duplicate writes are bit-identical MFMA results -> benign)
  const int ctb = (w < 4) ? 3 * w : 2 * w + 4;
  int ctv[3];
  ctv[0] = ctb;
  ctv[1] = (ctb + 1 < 19) ? ctb + 1 : 19;
  ctv[2] = (ctb + 2 < 19) ? ctb + 2 : 19;

  // --- stage x -> bf16 LDS; zero pad cols 320..343; zero own Pt pad cols 80..95 ---
  const float4* xin = reinterpret_cast<const float4*>(x + (size_t)(b * 4096 + q0) * 320);
  for (int i = tid; i < 64 * 80; i += 512) {
    float4 v = xin[i];
    int row = i / 80, c4 = (i - row * 80) * 4;
    ushort4 u;
    u.x = f2bf(v.x); u.y = f2bf(v.y); u.z = f2bf(v.z); u.w = f2bf(v.w);
    *reinterpret_cast<ushort4*>(&Qx[row][c4]) = u;
  }
  for (int i = tid; i < 64 * 3; i += 512) {
    int row = i / 3, q = i - row * 3;
    *reinterpret_cast<uint4*>(&Qx[row][320 + q * 8]) = (uint4){0u, 0u, 0u, 0u};
  }
  if (l < 32) {
    int r = l >> 1, q = l & 1;
    *reinterpret_cast<uint4*>(&Pt[w][r][80 + 8 * q]) = (uint4){0u, 0u, 0u, 0u};
  }
  __syncthreads();

  // --- Phase 1: Q-GEMM, all 64 rows x this wave's 3 col-tiles ---
  {
    f32x4 qacc[4][3];
    #pragma unroll
    for (int rt = 0; rt < 4; ++rt)
      #pragma unroll
      for (int nt = 0; nt < 3; ++nt) qacc[rt][nt] = (f32x4){0.f, 0.f, 0.f, 0.f};
    #pragma unroll
    for (int ks = 0; ks < 10; ++ks) {
      short8 af[4];
      #pragma unroll
      for (int rt = 0; rt < 4; ++rt)
        af[rt] = *reinterpret_cast<const short8*>(&Qx[rt * 16 + l16][ks * 32 + lhi * 8]);
      short8 bf[3];
      #pragma unroll
      for (int nt = 0; nt < 3; ++nt)
        bf[nt] = *reinterpret_cast<const short8*>(
            &wqt[(size_t)(ctv[nt] * 16 + l16) * 320 + ks * 32 + lhi * 8]);
      #pragma unroll
      for (int nt = 0; nt < 3; ++nt)
        #pragma unroll
        for (int rt = 0; rt < 4; ++rt)
          qacc[rt][nt] = __builtin_amdgcn_mfma_f32_16x16x32_bf16(af[rt], bf[nt], qacc[rt][nt], 0, 0, 0);
    }
    __syncthreads();   // all x reads done before overwrite
    #pragma unroll
    for (int nt = 0; nt < 3; ++nt) {
      int col = ctv[nt] * 16 + l16;
      #pragma unroll
      for (int rt = 0; rt < 4; ++rt)
        #pragma unroll
        for (int r = 0; r < 4; ++r)
          Qx[rt * 16 + lhi * 4 + r][col] = f2bf(qacc[rt][nt][r]);
    }
  }
  __syncthreads();

  // --- Phase 2: attention. wave = (row slice wq, head group hg), no barriers ---
  {
    const int wq = w & 3, hg = w >> 2;
    for (int hi = 0; hi < 4; ++hi) {
      const int h = hg * 4 + hi;
      const u16* kh = kbf + (size_t)(b * 8 + h) * 80 * 64;
      const u16* vh = vtp + (size_t)(b * 8 + h) * 48 * 96;
      // S = Q K^T (Q from LDS; k-overrun cols hold finite Q/O of next head, B-pad zeros kill them)
      f32x4 sacc[5];
      #pragma unroll
      for (int mt = 0; mt < 5; ++mt) sacc[mt] = (f32x4){0.f, 0.f, 0.f, 0.f};
      #pragma unroll
      for (int ks = 0; ks < 2; ++ks) {
        short8 a = *reinterpret_cast<const short8*>(&Qx[wq * 16 + l16][h * 40 + ks * 32 + lhi * 8]);
        #pragma unroll
        for (int mt = 0; mt < 5; ++mt) {
          short8 bb = *reinterpret_cast<const short8*>(&kh[(mt * 16 + l16) * 64 + ks * 32 + lhi * 8]);
          sacc[mt] = __builtin_amdgcn_mfma_f32_16x16x32_bf16(a, bb, sacc[mt], 0, 0, 0);
        }
      }
      // softmax without max-shift (scores ~N(0,1), SCALE folded; exp f32-safe)
      #pragma unroll
      for (int r = 0; r < 4; ++r) {
        float ev[5];
        float sum = 0.f;
        #pragma unroll
        for (int mt = 0; mt < 5; ++mt) {
          float s = (mt * 16 + l16 >= 77) ? -1e30f : sacc[mt][r];
          ev[mt] = __expf(s);
          sum += ev[mt];
        }
        sum += __shfl_xor(sum, 1);
        sum += __shfl_xor(sum, 2);
        sum += __shfl_xor(sum, 4);
        sum += __shfl_xor(sum, 8);
        float rs = 1.f / sum;
        int row = lhi * 4 + r;
        #pragma unroll
        for (int mt = 0; mt < 5; ++mt)
          Pt[w][row][mt * 16 + l16] = f2bf(ev[mt] * rs);
      }
      // fence: P writes (and this head's Q ds_reads) complete before PV reads / O overwrite
      asm volatile("s_waitcnt lgkmcnt(0)" ::: "memory");
      __builtin_amdgcn_sched_barrier(0);
      f32x4 oacc[3];
      #pragma unroll
      for (int nt = 0; nt < 3; ++nt) oacc[nt] = (f32x4){0.f, 0.f, 0.f, 0.f};
      #pragma unroll
      for (int ks = 0; ks < 3; ++ks) {
        short8 a = *reinterpret_cast<const short8*>(&Pt[w][l16][ks * 32 + lhi * 8]);
        #pragma unroll
        for (int nt = 0; nt < 3; ++nt) {
          short8 bb = *reinterpret_cast<const short8*>(&vh[(nt * 16 + l16) * 96 + ks * 32 + lhi * 8]);
          oacc[nt] = __builtin_amdgcn_mfma_f32_16x16x32_bf16(a, bb, oacc[nt], 0, 0, 0);
        }
      }
      // fence: P reads complete before next head's P writes (same wave)
      asm volatile("s_waitcnt lgkmcnt(0)" ::: "memory");
      __builtin_amdgcn_sched_barrier(0);
      // O -> Qx in place (own rows, head-h cols; Q of head h no longer needed)
      #pragma unroll
      for (int nt = 0; nt < 3; ++nt) {
        int d = nt * 16 + l16;
        if (d < 40) {
          #pragma unroll
          for (int r = 0; r < 4; ++r)
            Qx[wq * 16 + lhi * 4 + r][h * 40 + d] = f2bf(oacc[nt][r]);
        }
      }
    }
  }
  __syncthreads();

  // --- Phase 3: out = O @ Wo^T + bo (wave: rows 32*w2, cols 80*w4) ---
  {
    const int w2 = w >> 2, w4 = w & 3;
    f32x4 cacc[2][5];
    #pragma unroll
    for (int rt = 0; rt < 2; ++rt)
      #pragma unroll
      for (int nt = 0; nt < 5; ++nt) cacc[rt][nt] = (f32x4){0.f, 0.f, 0.f, 0.f};
    #pragma unroll
    for (int ks = 0; ks < 10; ++ks) {
      short8 af[2];
      #pragma unroll
      for (int rt = 0; rt < 2; ++rt)
        af[rt] = *reinterpret_cast<const short8*>(&Qx[w2 * 32 + rt * 16 + l16][ks * 32 + lhi * 8]);
      #pragma unroll
      for (int nt = 0; nt < 5; ++nt) {
        short8 bf = *reinterpret_cast<const short8*>(
            &wot[(size_t)(w4 * 80 + nt * 16 + l16) * 320 + ks * 32 + lhi * 8]);
        #pragma unroll
        for (int rt = 0; rt < 2; ++rt)
          cacc[rt][nt] = __builtin_amdgcn_mfma_f32_16x16x32_bf16(af[rt], bf, cacc[rt][nt], 0, 0, 0);
      }
    }
    #pragma unroll
    for (int nt = 0; nt < 5; ++nt) {
      int col = w4 * 80 + nt * 16 + l16;
      float bias = bo[col];
      #pragma unroll
      for (int rt = 0; rt < 2; ++rt) {
        #pragma unroll
        for (int r = 0; r < 4; ++r) {
          int row = w2 * 32 + rt * 16 + lhi * 4 + r;
          out[(size_t)(b * 4096 + q0 + row) * 320 + col] = cacc[rt][nt][r] + bias;
        }
      }
    }
  }
}

extern "C" void kernel_launch(void* const* d_in, const int* in_sizes, int n_in,
                              void* d_out, int out_size, void* d_ws, size_t ws_size,
                              hipStream_t stream) {
  (void)in_sizes; (void)n_in; (void)out_size; (void)ws_size;
  const float* x       = (const float*)d_in[0];
  const float* context = (const float*)d_in[1];
  const float* Wq      = (const float*)d_in[2];
  const float* Wk      = (const float*)d_in[3];
  const float* Wv      = (const float*)d_in[4];
  const float* Wo      = (const float*)d_in[5];
  const float* bo      = (const float*)d_in[6];
  float* out = (float*)d_out;
  u16* ws = (u16*)d_ws;
  u16* wqt = ws;                 // 102400
  u16* wot = ws + 102400;        // 102400
  u16* wkt = ws + 204800;        // 245760
  u16* wvt = ws + 450560;        // 245760
  u16* kbf = ws + 696320;        // 655360
  u16* vtp = ws + 1351680;       // 589824

  prep_transpose<<<170, 256, 0, stream>>>(Wq, Wo, Wk, Wv, wqt, wot, wkt, wvt);
  kv_mfma<<<dim3(16, 2), 256, 0, stream>>>(context, wkt, wvt, kbf, vtp);
  fused<<<dim3(64, 16), 512, 0, stream>>>(x, wqt, kbf, vtp, wot, bo, out);
}

// Round 12
// 188.202 us; speedup vs baseline: 1.2155x; 1.0113x over previous
//
#include <hip/hip_runtime.h>

typedef unsigned short u16;
using short8 = __attribute__((ext_vector_type(8))) short;
using f32x4  = __attribute__((ext_vector_type(4))) float;

#define SCALE 0.15811388300841897f  // 40^-0.5

__device__ __forceinline__ u16 f2bf(float f) {
  unsigned int u = __float_as_uint(f);
  u += 0x7fffu + ((u >> 16) & 1u);   // RNE
  return (u16)(u >> 16);
}

// ---------------- ws layout (u16 units) ----------------
// wqt [320][320]        @ 0        (102400)  Wq^T * SCALE, bf16
// wot [320][320]        @ 102400   (102400)  Wo^T, bf16
// wkt [320][768]        @ 204800   (245760)  Wk^T, bf16
// wvt [320][768]        @ 450560   (245760)  Wv^T, bf16
// kbf [16][8][80][64]   @ 696320   (655360)  K  (m pad->80, d pad->64 zeroed)
// vt  [16][8][48][96]   @ 1351680  (589824)  V^T (d pad->48 zeroed, m pad->96 zeroed)

// ============ kernel 0: LDS-tiled weight transpose + bf16 ============
__global__ void prep_transpose(const float* __restrict__ Wq, const float* __restrict__ Wo,
                               const float* __restrict__ Wk, const float* __restrict__ Wv,
                               u16* __restrict__ wqt, u16* __restrict__ wot,
                               u16* __restrict__ wkt, u16* __restrict__ wvt) {
  __shared__ float ld[64][65];
  const int bid = blockIdx.x;
  const float* src; u16* dst; int K; float scale; int tk, tn;
  if (bid < 25)       { src = Wq; dst = wqt; K = 320; scale = SCALE; tk = bid / 5;         tn = bid % 5; }
  else if (bid < 50)  { src = Wo; dst = wot; K = 320; scale = 1.f;   tk = (bid - 25) / 5;  tn = (bid - 25) % 5; }
  else if (bid < 110) { src = Wk; dst = wkt; K = 768; scale = 1.f;   tk = (bid - 50) / 5;  tn = (bid - 50) % 5; }
  else                { src = Wv; dst = wvt; K = 768; scale = 1.f;   tk = (bid - 110) / 5; tn = (bid - 110) % 5; }
  const int c = threadIdx.x & 63, r0 = threadIdx.x >> 6;
  for (int rr = r0; rr < 64; rr += 4)
    ld[rr][c] = src[(size_t)(tk * 64 + rr) * 320 + tn * 64 + c];
  __syncthreads();
  for (int rr = r0; rr < 64; rr += 4)
    dst[(size_t)(tn * 64 + rr) * K + tk * 64 + c] = f2bf(ld[c][rr] * scale);
}

// ============ kernel 1: K,V projection via MFMA (split K/V) ============
__global__ __launch_bounds__(256, 1)
void kv_mfma(const float* __restrict__ ctx,
             const u16* __restrict__ wkt, const u16* __restrict__ wvt,
             u16* __restrict__ kbf, u16* __restrict__ vt) {
  const int b = blockIdx.x, z = blockIdx.y;
  const int tid = threadIdx.x;
  const int w = tid >> 6, l = tid & 63, l16 = l & 15, lhi = l >> 4;
  __shared__ __align__(16) u16 sctx[80][776];

  for (int i = tid; i < 80 * 192; i += 256) {
    int row = i / 192, c4 = (i - row * 192) * 4;
    ushort4 u;
    if (row < 77) {
      float4 v = *reinterpret_cast<const float4*>(&ctx[(size_t)(b * 77 + row) * 768 + c4]);
      u.x = f2bf(v.x); u.y = f2bf(v.y); u.z = f2bf(v.z); u.w = f2bf(v.w);
    } else u = (ushort4){0, 0, 0, 0};
    *reinterpret_cast<ushort4*>(&sctx[row][c4]) = u;
  }
  if (z == 0) {
    for (int i = tid; i < 8 * 80 * 3; i += 256) {
      int hm = i / 3, q = i - hm * 3;
      int h = hm / 80, m = hm - h * 80;
      *reinterpret_cast<uint4*>(&kbf[(((size_t)b * 8 + h) * 80 + m) * 64 + 40 + q * 8]) = (uint4){0, 0, 0, 0};
    }
  } else {
    for (int i = tid; i < 8 * 48 * 2; i += 256) {
      int hd = i / 2, q = i - hd * 2;
      int h = hd / 48, d = hd - h * 48;
      *reinterpret_cast<uint4*>(&vt[(((size_t)b * 8 + h) * 48 + d) * 96 + 80 + q * 8]) = (uint4){0, 0, 0, 0};
    }
    for (int i = tid; i < 8 * 8 * 10; i += 256) {
      int h = i / 80, rem = i - h * 80;
      int d = 40 + rem / 10, q = rem - (rem / 10) * 10;
      *reinterpret_cast<uint4*>(&vt[(((size_t)b * 8 + h) * 48 + d) * 96 + q * 8]) = (uint4){0, 0, 0, 0};
    }
  }
  __syncthreads();

  f32x4 acc[5][5];
  #pragma unroll
  for (int rt = 0; rt < 5; ++rt)
    #pragma unroll
    for (int nt = 0; nt < 5; ++nt) acc[rt][nt] = (f32x4){0.f, 0.f, 0.f, 0.f};

  const u16* wbase = (z == 0 ? wkt : wvt) + (size_t)(w * 80) * 768;
  #pragma unroll 2
  for (int ks = 0; ks < 24; ++ks) {
    short8 af[5];
    #pragma unroll
    for (int rt = 0; rt < 5; ++rt)
      af[rt] = *reinterpret_cast<const short8*>(&sctx[rt * 16 + l16][ks * 32 + lhi * 8]);
    short8 bf[5];
    #pragma unroll
    for (int nt = 0; nt < 5; ++nt)
      bf[nt] = *reinterpret_cast<const short8*>(&wbase[(size_t)(nt * 16 + l16) * 768 + ks * 32 + lhi * 8]);
    #pragma unroll
    for (int rt = 0; rt < 5; ++rt)
      #pragma unroll
      for (int nt = 0; nt < 5; ++nt)
        acc[rt][nt] = __builtin_amdgcn_mfma_f32_16x16x32_bf16(af[rt], bf[nt], acc[rt][nt], 0, 0, 0);
  }

  if (z == 0) {
    #pragma unroll
    for (int rt = 0; rt < 5; ++rt)
      #pragma unroll
      for (int nt = 0; nt < 5; ++nt) {
        int c = w * 80 + nt * 16 + l16, h = c / 40, d = c - h * 40;
        #pragma unroll
        for (int r = 0; r < 4; ++r) {
          int m = rt * 16 + lhi * 4 + r;
          kbf[(((size_t)b * 8 + h) * 80 + m) * 64 + d] = f2bf(m < 77 ? acc[rt][nt][r] : 0.f);
        }
      }
  } else {
    #pragma unroll
    for (int rt = 0; rt < 5; ++rt)
      #pragma unroll
      for (int nt = 0; nt < 5; ++nt) {
        int c = w * 80 + nt * 16 + l16, h = c / 40, d = c - h * 40;
        #pragma unroll
        for (int r = 0; r < 4; ++r) {
          int m = rt * 16 + lhi * 4 + r;
          vt[(((size_t)b * 8 + h) * 48 + d) * 96 + m] = f2bf(m < 77 ? acc[rt][nt][r] : 0.f);
        }
      }
  }
}

// ============ kernel 2: fully fused x->Q->attention->out ============
// grid (64 qtiles, 16 b), 512 thr (8 waves), LDS 70.7 KB -> 2 blocks/CU.
// Phase 2 uses SWAPPED QK^T: mfma(A=K, B=Q) puts query q=lane&15 in columns;
// each lane owns 20 scores of one q-row (partitioned by lhi) -> softmax is
// 20 exp + 19 add + 2 shfl_xor + 1 rcp, P written as 10 ds_write_b32.
__global__ __launch_bounds__(512, 4)
void fused(const float* __restrict__ x, const u16* __restrict__ wqt,
           const u16* __restrict__ kbf, const u16* __restrict__ vtp,
           const u16* __restrict__ wot, const float* __restrict__ bo,
           float* __restrict__ out) {
  const int b  = blockIdx.y;
  const int q0 = blockIdx.x * 64;
  const int tid = threadIdx.x;
  const int w   = tid >> 6;       // 0..7
  const int l   = tid & 63;
  const int l16 = l & 15;
  const int lhi = l >> 4;

  __shared__ __align__(16) u16 Qx[64][344];      // 44,032 B: x -> Q -> O in place
  __shared__ __align__(16) u16 Pt[8][16][104];   // 26,624 B: per-wave P

  const int ctb = (w < 4) ? 3 * w : 2 * w + 4;
  int ctv[3];
  ctv[0] = ctb;
  ctv[1] = (ctb + 1 < 19) ? ctb + 1 : 19;
  ctv[2] = (ctb + 2 < 19) ? ctb + 2 : 19;

  // --- stage x -> bf16 LDS; zero pad cols 320..343; zero own Pt pad cols 80..95 ---
  const float4* xin = reinterpret_cast<const float4*>(x + (size_t)(b * 4096 + q0) * 320);
  for (int i = tid; i < 64 * 80; i += 512) {
    float4 v = xin[i];
    int row = i / 80, c4 = (i - row * 80) * 4;
    ushort4 u;
    u.x = f2bf(v.x); u.y = f2bf(v.y); u.z = f2bf(v.z); u.w = f2bf(v.w);
    *reinterpret_cast<ushort4*>(&Qx[row][c4]) = u;
  }
  for (int i = tid; i < 64 * 3; i += 512) {
    int row = i / 3, q = i - row * 3;
    *reinterpret_cast<uint4*>(&Qx[row][320 + q * 8]) = (uint4){0u, 0u, 0u, 0u};
  }
  if (l < 32) {
    int r = l >> 1, q = l & 1;
    *reinterpret_cast<uint4*>(&Pt[w][r][80 + 8 * q]) = (uint4){0u, 0u, 0u, 0u};
  }
  __syncthreads();

  // --- Phase 1: Q-GEMM, all 64 rows x this wave's 3 col-tiles ---
  {
    f32x4 qacc[4][3];
    #pragma unroll
    for (int rt = 0; rt < 4; ++rt)
      #pragma unroll
      for (int nt = 0; nt < 3; ++nt) qacc[rt][nt] = (f32x4){0.f, 0.f, 0.f, 0.f};
    #pragma unroll
    for (int ks = 0; ks < 10; ++ks) {
      short8 af[4];
      #pragma unroll
      for (int rt = 0; rt < 4; ++rt)
        af[rt] = *reinterpret_cast<const short8*>(&Qx[rt * 16 + l16][ks * 32 + lhi * 8]);
      short8 bf[3];
      #pragma unroll
      for (int nt = 0; nt < 3; ++nt)
        bf[nt] = *reinterpret_cast<const short8*>(
            &wqt[(size_t)(ctv[nt] * 16 + l16) * 320 + ks * 32 + lhi * 8]);
      #pragma unroll
      for (int nt = 0; nt < 3; ++nt)
        #pragma unroll
        for (int rt = 0; rt < 4; ++rt)
          qacc[rt][nt] = __builtin_amdgcn_mfma_f32_16x16x32_bf16(af[rt], bf[nt], qacc[rt][nt], 0, 0, 0);
    }
    __syncthreads();   // all x reads done before overwrite
    #pragma unroll
    for (int nt = 0; nt < 3; ++nt) {
      int col = ctv[nt] * 16 + l16;
      #pragma unroll
      for (int rt = 0; rt < 4; ++rt)
        #pragma unroll
        for (int r = 0; r < 4; ++r)
          Qx[rt * 16 + lhi * 4 + r][col] = f2bf(qacc[rt][nt][r]);
    }
  }
  __syncthreads();

  // --- Phase 2: attention, swapped QK^T. wave = (rows wq*16.., heads hg*4..) ---
  {
    const int wq = w & 3, hg = w >> 2;
    // hoist Q fragments for all 4 heads into registers (B-operand of swapped QK)
    short8 qf[4][2];
    #pragma unroll
    for (int hi = 0; hi < 4; ++hi)
      #pragma unroll
      for (int ks = 0; ks < 2; ++ks)
        qf[hi][ks] = *reinterpret_cast<const short8*>(
            &Qx[wq * 16 + l16][(hg * 4 + hi) * 40 + ks * 32 + lhi * 8]);

    for (int hi = 0; hi < 4; ++hi) {
      const int h = hg * 4 + hi;
      const u16* kh = kbf + (size_t)(b * 8 + h) * 80 * 64;
      const u16* vh = vtp + (size_t)(b * 8 + h) * 48 * 96;
      // S^T = K @ Q^T: lane (l16,lhi) holds S[m = mt*16 + lhi*4 + r][q = l16]
      f32x4 sacc[5];
      #pragma unroll
      for (int mt = 0; mt < 5; ++mt) sacc[mt] = (f32x4){0.f, 0.f, 0.f, 0.f};
      #pragma unroll
      for (int ks = 0; ks < 2; ++ks) {
        #pragma unroll
        for (int mt = 0; mt < 5; ++mt) {
          short8 ka = *reinterpret_cast<const short8*>(&kh[(mt * 16 + l16) * 64 + ks * 32 + lhi * 8]);
          sacc[mt] = __builtin_amdgcn_mfma_f32_16x16x32_bf16(ka, qf[hi][ks], sacc[mt], 0, 0, 0);
        }
      }
      // prefetch V ks=0 (independent; hides under softmax)
      short8 vb0[3];
      #pragma unroll
      for (int nt = 0; nt < 3; ++nt)
        vb0[nt] = *reinterpret_cast<const short8*>(&vh[(nt * 16 + l16) * 96 + lhi * 8]);
      // lane-local softmax (no max-shift: scores ~N(0,1), SCALE folded)
      float ev[5][4];
      float psum = 0.f;
      #pragma unroll
      for (int mt = 0; mt < 5; ++mt)
        #pragma unroll
        for (int r = 0; r < 4; ++r) {
          float e = __expf(sacc[mt][r]);
          if (mt == 4 && lhi * 4 + r >= 13) e = 0.f;   // m = 64+lhi*4+r >= 77
          ev[mt][r] = e;
          psum += e;
        }
      psum += __shfl_xor(psum, 16);
      psum += __shfl_xor(psum, 32);
      float rs = 1.f / psum;
      // WAR fence: previous head's P reads done before overwriting P
      // (drain hides under this head's QK + softmax)
      asm volatile("s_waitcnt lgkmcnt(0)" ::: "memory");
      // pack & write P: lane writes its q-row (row=l16), m = mt*16 + lhi*4 + 2j
      #pragma unroll
      for (int mt = 0; mt < 5; ++mt)
        #pragma unroll
        for (int j = 0; j < 2; ++j) {
          unsigned pk = (unsigned)f2bf(ev[mt][2 * j] * rs) |
                        ((unsigned)f2bf(ev[mt][2 * j + 1] * rs) << 16);
          *reinterpret_cast<unsigned*>(&Pt[w][l16][mt * 16 + lhi * 4 + 2 * j]) = pk;
        }
      // RAW fence: P writes visible before PV reads (same wave)
      asm volatile("s_waitcnt lgkmcnt(0)" ::: "memory");
      __builtin_amdgcn_sched_barrier(0);
      // O = P @ V (A-frag from LDS, standard orientation)
      f32x4 oacc[3];
      #pragma unroll
      for (int nt = 0; nt < 3; ++nt) oacc[nt] = (f32x4){0.f, 0.f, 0.f, 0.f};
      #pragma unroll
      for (int ks = 0; ks < 3; ++ks) {
        short8 a = *reinterpret_cast<const short8*>(&Pt[w][l16][ks * 32 + lhi * 8]);
        #pragma unroll
        for (int nt = 0; nt < 3; ++nt) {
          short8 bb = (ks == 0) ? vb0[nt]
                                : *reinterpret_cast<const short8*>(&vh[(nt * 16 + l16) * 96 + ks * 32 + lhi * 8]);
          oacc[nt] = __builtin_amdgcn_mfma_f32_16x16x32_bf16(a, bb, oacc[nt], 0, 0, 0);
        }
      }
      // O -> Qx in place (own rows, head-h cols). No fence: targets Qx, not Pt;
      // next head's Pt WAR is covered by the loop-top fence.
      #pragma unroll
      for (int nt = 0; nt < 3; ++nt) {
        int d = nt * 16 + l16;
        if (d < 40) {
          #pragma unroll
          for (int r = 0; r < 4; ++r)
            Qx[wq * 16 + lhi * 4 + r][h * 40 + d] = f2bf(oacc[nt][r]);
        }
      }
    }
  }
  __syncthreads();

  // --- Phase 3: out = O @ Wo^T + bo (wave: rows 32*w2, cols 80*w4) ---
  {
    const int w2 = w >> 2, w4 = w & 3;
    f32x4 cacc[2][5];
    #pragma unroll
    for (int rt = 0; rt < 2; ++rt)
      #pragma unroll
      for (int nt = 0; nt < 5; ++nt) cacc[rt][nt] = (f32x4){0.f, 0.f, 0.f, 0.f};
    #pragma unroll
    for (int ks = 0; ks < 10; ++ks) {
      short8 af[2];
      #pragma unroll
      for (int rt = 0; rt < 2; ++rt)
        af[rt] = *reinterpret_cast<const short8*>(&Qx[w2 * 32 + rt * 16 + l16][ks * 32 + lhi * 8]);
      #pragma unroll
      for (int nt = 0; nt < 5; ++nt) {
        short8 bf = *reinterpret_cast<const short8*>(
            &wot[(size_t)(w4 * 80 + nt * 16 + l16) * 320 + ks * 32 + lhi * 8]);
        #pragma unroll
        for (int rt = 0; rt < 2; ++rt)
          cacc[rt][nt] = __builtin_amdgcn_mfma_f32_16x16x32_bf16(af[rt], bf, cacc[rt][nt], 0, 0, 0);
      }
    }
    #pragma unroll
    for (int nt = 0; nt < 5; ++nt) {
      int col = w4 * 80 + nt * 16 + l16;
      float bias = bo[col];
      #pragma unroll
      for (int rt = 0; rt < 2; ++rt) {
        #pragma unroll
        for (int r = 0; r < 4; ++r) {
          int row = w2 * 32 + rt * 16 + lhi * 4 + r;
          out[(size_t)(b * 4096 + q0 + row) * 320 + col] = cacc[rt][nt][r] + bias;
        }
      }
    }
  }
}

extern "C" void kernel_launch(void* const* d_in, const int* in_sizes, int n_in,
                              void* d_out, int out_size, void* d_ws, size_t ws_size,
                              hipStream_t stream) {
  (void)in_sizes; (void)n_in; (void)out_size; (void)ws_size;
  const float* x       = (const float*)d_in[0];
  const float* context = (const float*)d_in[1];
  const float* Wq      = (const float*)d_in[2];
  const float* Wk      = (const float*)d_in[3];
  const float* Wv      = (const float*)d_in[4];
  const float* Wo      = (const float*)d_in[5];
  const float* bo      = (const float*)d_in[6];
  float* out = (float*)d_out;
  u16* ws = (u16*)d_ws;
  u16* wqt = ws;                 // 102400
  u16* wot = ws + 102400;        // 102400
  u16* wkt = ws + 204800;        // 245760
  u16* wvt = ws + 450560;        // 245760
  u16* kbf = ws + 696320;        // 655360
  u16* vtp = ws + 1351680;       // 589824

  prep_transpose<<<170, 256, 0, stream>>>(Wq, Wo, Wk, Wv, wqt, wot, wkt, wvt);
  kv_mfma<<<dim3(16, 2), 256, 0, stream>>>(context, wkt, wvt, kbf, vtp);
  fused<<<dim3(64, 16), 512, 0, stream>>>(x, wqt, kbf, vtp, wot, bo, out);
}